// Round 6
// baseline (370.423 us; speedup 1.0000x reference)
//
#include <hip/hip_runtime.h>
#include <hip/hip_bf16.h>
#include <cstdint>
#include <cstddef>

// ---------------- problem constants ----------------
#define B_  4
#define L_  4096
#define D_  256
#define DI_ 512
#define H_  8
#define P_  64
#define N_  16
#define M_  (B_ * L_)              // 16384 rows
#define PROJ_ (DI_ + 2 * H_ * N_)  // 768

// chunked scan parameters (1 thread = 1 (b,h,p) channel, 16 states)
#define NC_ 64                     // chunks along L
#define CL_ (L_ / NC_)             // 64
#define NSEQ_ (B_ * H_ * P_ * N_)  // 32768 scalar sequences
#define LOG2E_ 1.4426950408889634f

typedef __bf16 bf16x8 __attribute__((ext_vector_type(8)));
typedef __bf16 bf16x4 __attribute__((ext_vector_type(4)));
typedef float f32x4 __attribute__((ext_vector_type(4)));
typedef float f32x2 __attribute__((ext_vector_type(2)));
typedef _Float16 f16x8 __attribute__((ext_vector_type(8)));

__device__ __forceinline__ void cp16_lds(const __hip_bfloat16* g, short* lds) {
    __builtin_amdgcn_global_load_lds(
        (const __attribute__((address_space(1))) void*)g,
        (__attribute__((address_space(3))) void*)lds, 16, 0, 0);
}

// R6: packed fp32 VALU (VOP3P). Scan kernels are VALU-bound (R3: VALUBusy 73%);
// 2 fp32 lanes/instr halves the scan inner-loop op count.
__device__ __forceinline__ f32x2 pk_fma(f32x2 a, f32x2 b, f32x2 c) {
    f32x2 d;
    asm("v_pk_fma_f32 %0, %1, %2, %3" : "=v"(d) : "v"(a), "v"(b), "v"(c));
    return d;
}
__device__ __forceinline__ f32x2 pk_mul(f32x2 a, f32x2 b) {
    f32x2 d;
    asm("v_pk_mul_f32 %0, %1, %2" : "=v"(d) : "v"(a), "v"(b));
    return d;
}

// ---------------- fp32 -> bf16 conversion, weights only ----------------------
#define WS1 (2 * DI_ * D_)     // in_proj_w    262144
#define WS2 (PROJ_ * DI_)      // x_proj_w     393216
#define WS3 (D_ * DI_)         // out_proj_w   131072
#define WC1 (WS1)
#define WC2 (WC1 + WS2)
#define WC3 (WC2 + WS3)
#define WC4 (WC3 + WS1)
#define WC5 (WC4 + WS2)
#define WC6 (WC5 + WS3)        // 1572864 total

__launch_bounds__(256)
__global__ void f2b_all(const float* __restrict__ i1,
                        const float* __restrict__ i2, const float* __restrict__ i3,
                        const float* __restrict__ i4, const float* __restrict__ i5,
                        const float* __restrict__ i6,
                        __hip_bfloat16* o1, __hip_bfloat16* o2,
                        __hip_bfloat16* o3, __hip_bfloat16* o4, __hip_bfloat16* o5,
                        __hip_bfloat16* o6) {
    for (int idx = blockIdx.x * 256 + threadIdx.x; idx < WC6; idx += gridDim.x * 256) {
        const float* s; __hip_bfloat16* d; int off;
        if (idx < WC1)      { s = i1; d = o1; off = idx; }
        else if (idx < WC2) { s = i2; d = o2; off = idx - WC1; }
        else if (idx < WC3) { s = i3; d = o3; off = idx - WC2; }
        else if (idx < WC4) { s = i4; d = o4; off = idx - WC3; }
        else if (idx < WC5) { s = i5; d = o5; off = idx - WC4; }
        else                { s = i6; d = o6; off = idx - WC5; }
        d[off] = __float2bfloat16(s[off]);
    }
}

// ---------------- MFMA bf16 GEMM 128x128: C = A * W^T + bias -----------------
// BK=64, XOR-swizzled LDS -> conflict-free ds_read_b128.
// AF32=1: A read as fp32; pre-swizzled global src + linear ds_write.
// EPI 1: in_proj: col<DI -> silu -> obf bf16 (xi, ld 512); else z bf16 (zb)
// EPI 2: x_proj: col<DI -> softplus(v+aux); bf16 store to obf (ld 768)
template <int EPI, int AF32>
__launch_bounds__(256)
__global__ void gemm_mfma(const __hip_bfloat16* __restrict__ A,
                          const __hip_bfloat16* __restrict__ W,
                          const float* __restrict__ bias, int Kv,
                          __hip_bfloat16* __restrict__ zb,
                          __hip_bfloat16* __restrict__ obf,
                          const float* __restrict__ aux,
                          const float* __restrict__ A32) {
    __shared__ short As[128 * 64];   // 16 KB
    __shared__ short Bs[128 * 64];   // 16 KB
    const int tid = threadIdx.x;
    const int lane = tid & 63;
    const int wave = tid >> 6;
    const int bm = blockIdx.x * 128;
    const int bn = blockIdx.y * 128;
    const int wm = (wave >> 1) * 64;
    const int wn = (wave & 1) * 64;

    f32x4 acc[4][4];
#pragma unroll
    for (int i = 0; i < 4; ++i)
#pragma unroll
        for (int j = 0; j < 4; ++j) acc[i][j] = (f32x4)0.f;

    const int srow = lane >> 3;                       // 0..7
    const int sx = lane & 7;
    const int ssegx = (sx ^ srow) * 8;                // swizzled k offset (shorts)
    const __hip_bfloat16* gA0 = A + (size_t)(bm + wave * 32 + srow) * Kv + ssegx;
    const __hip_bfloat16* gB0 = W + (size_t)(bn + wave * 32 + srow) * Kv + ssegx;
    short* lA0 = As + (wave * 32) * 64;
    short* lB0 = Bs + (wave * 32) * 64;

    const int fr = lane & 15;        // fragment row within 16
    const int kq = lane >> 4;        // k-quarter 0..3

    for (int k0 = 0; k0 < Kv; k0 += 64) {
        if (AF32) {
#pragma unroll
            for (int rb = 0; rb < 4; ++rb) {
                const int row = wave * 32 + rb * 8 + srow;
                // pre-swizzled global source; linear LDS dest (conflict-free)
                const float* g = A32 + (size_t)(bm + row) * Kv + k0 + ssegx;
                const float4 f0 = *reinterpret_cast<const float4*>(g);
                const float4 f1 = *reinterpret_cast<const float4*>(g + 4);
                bf16x8 s;
                s[0] = (__bf16)f0.x; s[1] = (__bf16)f0.y;
                s[2] = (__bf16)f0.z; s[3] = (__bf16)f0.w;
                s[4] = (__bf16)f1.x; s[5] = (__bf16)f1.y;
                s[6] = (__bf16)f1.z; s[7] = (__bf16)f1.w;
                *reinterpret_cast<bf16x8*>(&As[row * 64 + sx * 8]) = s;
            }
        } else {
#pragma unroll
            for (int rb = 0; rb < 4; ++rb)
                cp16_lds(gA0 + (size_t)(rb * 8) * Kv + k0, lA0 + rb * 8 * 64);
        }
#pragma unroll
        for (int rb = 0; rb < 4; ++rb)
            cp16_lds(gB0 + (size_t)(rb * 8) * Kv + k0, lB0 + rb * 8 * 64);
        __syncthreads();
#pragma unroll
        for (int ks = 0; ks < 2; ++ks) {
            const int kgg = ks * 4 + kq;                       // 0..7
            const int kslot = (kgg ^ (fr & 7)) * 8;            // un-swizzle
            bf16x8 af[4], bv[4];
#pragma unroll
            for (int i = 0; i < 4; ++i)
                af[i] = *reinterpret_cast<const bf16x8*>(
                    &As[(wm + i * 16 + fr) * 64 + kslot]);
#pragma unroll
            for (int j = 0; j < 4; ++j)
                bv[j] = *reinterpret_cast<const bf16x8*>(
                    &Bs[(wn + j * 16 + fr) * 64 + kslot]);
#pragma unroll
            for (int i = 0; i < 4; ++i)
#pragma unroll
                for (int j = 0; j < 4; ++j)
                    acc[i][j] = __builtin_amdgcn_mfma_f32_16x16x32_bf16(
                        af[i], bv[j], acc[i][j], 0, 0, 0);
        }
        __syncthreads();
    }

    const int n16 = lane & 15;
    const int r4 = (lane >> 4) * 4;
#pragma unroll
    for (int i = 0; i < 4; ++i) {
#pragma unroll
        for (int j = 0; j < 4; ++j) {
            const int cg = bn + wn + j * 16 + n16;
            const float bb = bias[cg];
#pragma unroll
            for (int v = 0; v < 4; ++v) {
                const int r = bm + wm + i * 16 + r4 + v;
                float val = acc[i][j][v] + bb;
                if (EPI == 1) {
                    if (cg < DI_) {
                        val = val / (1.f + __expf(-val));
                        obf[(size_t)r * DI_ + cg] = __float2bfloat16(val);
                    } else {
                        zb[(size_t)r * DI_ + cg - DI_] = __float2bfloat16(val);
                    }
                } else {  // EPI 2: all-bf16 proj store
                    if (cg < DI_) {
                        const float x = val + aux[cg];
                        val = (x > 20.f) ? x : __logf(1.f + __expf(x));
                    }
                    obf[(size_t)r * PROJ_ + cg] = __float2bfloat16(val);
                }
            }
        }
    }
}

// ---------------- small-tile GEMM 64x64: bwd out_proj + conv/GELU ------------
__launch_bounds__(256)
__global__ void gemm64_convout(const __hip_bfloat16* __restrict__ A,
                               const __hip_bfloat16* __restrict__ W,
                               const float* __restrict__ bias, int Kv,
                               float* __restrict__ out0,
                               const float* __restrict__ cw,
                               const float* __restrict__ cb,
                               const float* __restrict__ cinp) {
    __shared__ short As[64 * 64];    // 8 KB
    __shared__ short Bs[64 * 64];    // 8 KB
    const int tid = threadIdx.x;
    const int lane = tid & 63;
    const int wave = tid >> 6;
    const int bm = blockIdx.x * 64;
    const int bn = blockIdx.y * 64;
    const int wm = (wave >> 1) * 32;
    const int wn = (wave & 1) * 32;

    f32x4 acc[2][2];
#pragma unroll
    for (int i = 0; i < 2; ++i)
#pragma unroll
        for (int j = 0; j < 2; ++j) acc[i][j] = (f32x4)0.f;

    const int srow = lane >> 3;
    const int ssegx = ((lane & 7) ^ srow) * 8;
    const __hip_bfloat16* gA0 = A + (size_t)(bm + wave * 16 + srow) * Kv + ssegx;
    const __hip_bfloat16* gB0 = W + (size_t)(bn + wave * 16 + srow) * Kv + ssegx;
    short* lA0 = As + (wave * 16) * 64;
    short* lB0 = Bs + (wave * 16) * 64;

    const int fr = lane & 15;
    const int kq = lane >> 4;

    for (int k0 = 0; k0 < Kv; k0 += 64) {
#pragma unroll
        for (int rb = 0; rb < 2; ++rb) {
            cp16_lds(gA0 + (size_t)(rb * 8) * Kv + k0, lA0 + rb * 8 * 64);
            cp16_lds(gB0 + (size_t)(rb * 8) * Kv + k0, lB0 + rb * 8 * 64);
        }
        __syncthreads();
#pragma unroll
        for (int ks = 0; ks < 2; ++ks) {
            const int kgg = ks * 4 + kq;
            const int kslot = (kgg ^ (fr & 7)) * 8;
            bf16x8 af[2], bv[2];
#pragma unroll
            for (int i = 0; i < 2; ++i)
                af[i] = *reinterpret_cast<const bf16x8*>(
                    &As[(wm + i * 16 + fr) * 64 + kslot]);
#pragma unroll
            for (int j = 0; j < 2; ++j)
                bv[j] = *reinterpret_cast<const bf16x8*>(
                    &Bs[(wn + j * 16 + fr) * 64 + kslot]);
#pragma unroll
            for (int i = 0; i < 2; ++i)
#pragma unroll
                for (int j = 0; j < 2; ++j)
                    acc[i][j] = __builtin_amdgcn_mfma_f32_16x16x32_bf16(
                        af[i], bv[j], acc[i][j], 0, 0, 0);
        }
        __syncthreads();
    }

    const int n16 = lane & 15;
    const int r4 = (lane >> 4) * 4;
#pragma unroll
    for (int i = 0; i < 2; ++i) {
#pragma unroll
        for (int j = 0; j < 2; ++j) {
            const int cg = bn + wn + j * 16 + n16;
            const float bb = bias[cg];
#pragma unroll
            for (int v = 0; v < 4; ++v) {
                const int r = bm + wm + i * 16 + r4 + v;
                float val = acc[i][j][v] + bb;
                const int b = r >> 12;
                const int l = r & (L_ - 1);
                const int lo = L_ - 1 - l;
                const size_t base = ((size_t)(b << 12) + lo) * 256 + cg;
                float cv = fmaf(cinp[base], cw[cg * 3 + 1], cb[cg]);
                if (lo > 0) cv = fmaf(cinp[base - 256], cw[cg * 3 + 0], cv);
                if (lo + 1 < L_) cv = fmaf(cinp[base + 256], cw[cg * 3 + 2], cv);
                const float g = 0.5f * cv * (1.f + erff(cv * 0.70710678118654752f));
                out0[base] = val + g;
            }
        }
    }
}

// ---------------- fwd out_proj + LayerNorm + flip, 64-row tiles --------------
__launch_bounds__(256)
__global__ void gemm_out_ln(const __hip_bfloat16* __restrict__ A,
                            const __hip_bfloat16* __restrict__ W,
                            const float* __restrict__ bias,
                            const float* __restrict__ lnw,
                            const float* __restrict__ lnb,
                            __hip_bfloat16* __restrict__ outb) {
    __shared__ short As[64 * 64];     // 8 KB
    __shared__ short Ws[256 * 64];    // 32 KB
    __shared__ float rs[2][4][64];    // 2 KB row partial sums
    const int tid = threadIdx.x;
    const int lane = tid & 63;
    const int wave = tid >> 6;
    const int bm = blockIdx.x * 64;
    const int Kv = DI_;

    f32x4 acc[4][4];
#pragma unroll
    for (int i = 0; i < 4; ++i)
#pragma unroll
        for (int j = 0; j < 4; ++j) acc[i][j] = (f32x4)0.f;

    const int srow = lane >> 3;
    const int ssegx = ((lane & 7) ^ srow) * 8;
    const __hip_bfloat16* gA0 = A + (size_t)(bm + wave * 16 + srow) * Kv + ssegx;
    const __hip_bfloat16* gW0 = W + (size_t)(wave * 64 + srow) * Kv + ssegx;
    short* lA0 = As + (wave * 16) * 64;
    short* lW0 = Ws + (wave * 64) * 64;

    const int fr = lane & 15;
    const int kq = lane >> 4;

    for (int k0 = 0; k0 < Kv; k0 += 64) {
#pragma unroll
        for (int rb = 0; rb < 2; ++rb)
            cp16_lds(gA0 + (size_t)(rb * 8) * Kv + k0, lA0 + rb * 8 * 64);
#pragma unroll
        for (int rb = 0; rb < 8; ++rb)
            cp16_lds(gW0 + (size_t)(rb * 8) * Kv + k0, lW0 + rb * 8 * 64);
        __syncthreads();
#pragma unroll
        for (int ks = 0; ks < 2; ++ks) {
            const int kgg = ks * 4 + kq;
            const int kslot = (kgg ^ (fr & 7)) * 8;
            bf16x8 af[4], bv[4];
#pragma unroll
            for (int i = 0; i < 4; ++i)
                af[i] = *reinterpret_cast<const bf16x8*>(
                    &As[(i * 16 + fr) * 64 + kslot]);
#pragma unroll
            for (int j = 0; j < 4; ++j)
                bv[j] = *reinterpret_cast<const bf16x8*>(
                    &Ws[(wave * 64 + j * 16 + fr) * 64 + kslot]);
#pragma unroll
            for (int i = 0; i < 4; ++i)
#pragma unroll
                for (int j = 0; j < 4; ++j)
                    acc[i][j] = __builtin_amdgcn_mfma_f32_16x16x32_bf16(
                        af[i], bv[j], acc[i][j], 0, 0, 0);
        }
        __syncthreads();
    }

    const int n16 = lane & 15;
    const int r4 = (lane >> 4) * 4;
#pragma unroll
    for (int j = 0; j < 4; ++j) {
        const float bb = bias[wave * 64 + j * 16 + n16];
#pragma unroll
        for (int i = 0; i < 4; ++i)
#pragma unroll
            for (int v = 0; v < 4; ++v) acc[i][j][v] += bb;
    }

    // per-wave row partial sums over this wave's 64-col slice
#pragma unroll
    for (int i = 0; i < 4; ++i) {
#pragma unroll
        for (int v = 0; v < 4; ++v) {
            float s = 0.f, s2 = 0.f;
#pragma unroll
            for (int j = 0; j < 4; ++j) {
                const float t = acc[i][j][v];
                s += t; s2 = fmaf(t, t, s2);
            }
            s += __shfl_xor(s, 1); s2 += __shfl_xor(s2, 1);
            s += __shfl_xor(s, 2); s2 += __shfl_xor(s2, 2);
            s += __shfl_xor(s, 4); s2 += __shfl_xor(s2, 4);
            s += __shfl_xor(s, 8); s2 += __shfl_xor(s2, 8);
            if (n16 == 0) {
                rs[0][wave][i * 16 + r4 + v] = s;
                rs[1][wave][i * 16 + r4 + v] = s2;
            }
        }
    }
    __syncthreads();

#pragma unroll
    for (int i = 0; i < 4; ++i) {
#pragma unroll
        for (int v = 0; v < 4; ++v) {
            const int row = i * 16 + r4 + v;
            const float ts = rs[0][0][row] + rs[0][1][row] + rs[0][2][row] + rs[0][3][row];
            const float ts2 = rs[1][0][row] + rs[1][1][row] + rs[1][2][row] + rs[1][3][row];
            const float mean = ts * (1.f / 256.f);
            const float var = ts2 * (1.f / 256.f) - mean * mean;
            const float inv = rsqrtf(var + 1e-5f);
            const int rg = bm + row;
            const int b = rg >> 12;
            const int l = rg & (L_ - 1);
            const size_t drow = (size_t)((b << 12) + (L_ - 1 - l)) * 256;
#pragma unroll
            for (int j = 0; j < 4; ++j) {
                const int cg = wave * 64 + j * 16 + n16;
                const float o = (acc[i][j][v] - mean) * inv * lnw[cg] + lnb[cg];
                outb[drow + cg] = __float2bfloat16(o);
            }
        }
    }
}

// ---------------- chunked selective scan --------------------------------------
__device__ __forceinline__ bool a_is_arith(const float* A2) {
    bool ok = true;
#pragma unroll
    for (int n = 1; n < N_; ++n)
        ok = ok && (fabsf(A2[n] - (float)(n + 1) * A2[0]) <= 1e-4f * fabsf(A2[n]));
    return ok;
}

__launch_bounds__(256)
__global__ void scan_chunk_state(const __hip_bfloat16* __restrict__ xi,
                                 const __hip_bfloat16* __restrict__ projb,
                                 const float* __restrict__ A_log,
                                 float* __restrict__ sS,
                                 _Float16* __restrict__ st_hend) {
    __shared__ float bsh[4][CL_][16];   // 16 KB: per-wave B cache
    const int bh = blockIdx.x;
    const int b = bh >> 3;
    const int h = bh & 7;
    const int lane = threadIdx.x & 63;
    const int wave = threadIdx.x >> 6;
    const int chunk = blockIdx.y * 4 + wave;
    const int t0 = chunk * CL_;
    const int c = h * P_ + lane;
    const int bOff = DI_ + h * N_;

    // register-stage B (bf16 -> fp32 LDS), linear lane->dest (conflict-free)
    {
#pragma unroll
        for (int r = 0; r < 4; ++r) {
            const int stp = r * 16 + (lane >> 2);
            const int j = (lane & 3) * 4;
            const bf16x4 v = *reinterpret_cast<const bf16x4*>(
                projb + ((size_t)b * L_ + t0 + stp) * PROJ_ + bOff + j);
            *reinterpret_cast<float4*>(&bsh[wave][stp][j]) =
                make_float4((float)v[0], (float)v[1], (float)v[2], (float)v[3]);
        }
    }

    float A2[N_];
#pragma unroll
    for (int n = 0; n < N_; ++n)
        A2[n] = -__expf(A_log[c * N_ + n]) * LOG2E_;
    const bool fast = a_is_arith(A2);

    const __hip_bfloat16* pDt = projb + ((size_t)b * L_ + t0) * PROJ_ + c;
    const __hip_bfloat16* px = xi + ((size_t)b * L_ + t0) * DI_ + c;
    float S = 0.f;
    float hs[N_];
#pragma unroll
    for (int n = 0; n < N_; ++n) hs[n] = 0.f;

    if (fast) {
        // R6: packed fp32 — 8 float2 state pairs; dA pairs (e1,e2)x(e2,e2)^k
        f32x2 hp[8];
#pragma unroll
        for (int p = 0; p < 8; ++p) hp[p] = (f32x2)0.f;
        float dtb[2][4], xb[2][4];
#pragma unroll
        for (int i = 0; i < 4; ++i) {
            dtb[0][i] = __bfloat162float(pDt[(size_t)i * PROJ_]);
            xb[0][i] = __bfloat162float(px[(size_t)i * DI_]);
        }
#pragma unroll
        for (int k = 0; k < CL_ / 4; ++k) {
            const int cur = k & 1, nxt = cur ^ 1;
            if (k + 1 < CL_ / 4) {
#pragma unroll
                for (int i = 0; i < 4; ++i) {
                    dtb[nxt][i] = __bfloat162float(pDt[(size_t)((k + 1) * 4 + i) * PROJ_]);
                    xb[nxt][i] = __bfloat162float(px[(size_t)((k + 1) * 4 + i) * DI_]);
                }
            }
#pragma unroll
            for (int i = 0; i < 4; ++i) {
                const int t = k * 4 + i;
                const float dt_v = dtb[cur][i];
                const float dtx = dt_v * xb[cur][i];
                const float e1 = exp2f(dt_v * A2[0]);
                const float e2 = e1 * e1;
                S += dt_v;
                f32x2 dp; dp[0] = e1; dp[1] = e2;
                f32x2 mm; mm[0] = e2; mm[1] = e2;
                f32x2 dd; dd[0] = dtx; dd[1] = dtx;
                const f32x4* bp = reinterpret_cast<const f32x4*>(&bsh[wave][t][0]);
#pragma unroll
                for (int q = 0; q < 4; ++q) {
                    const f32x4 Bq = bp[q];
                    f32x2 b0; b0[0] = Bq[0]; b0[1] = Bq[1];
                    f32x2 b1; b1[0] = Bq[2]; b1[1] = Bq[3];
                    hp[2 * q] = pk_fma(hp[2 * q], dp, pk_mul(dd, b0));
                    dp = pk_mul(dp, mm);
                    hp[2 * q + 1] = pk_fma(hp[2 * q + 1], dp, pk_mul(dd, b1));
                    dp = pk_mul(dp, mm);
                }
            }
        }
#pragma unroll
        for (int p = 0; p < 8; ++p) { hs[2 * p] = hp[p][0]; hs[2 * p + 1] = hp[p][1]; }
    } else {
#pragma unroll 4
        for (int t = 0; t < CL_; ++t) {
            const float dt_v = __bfloat162float(pDt[(size_t)t * PROJ_]);
            const float xv = __bfloat162float(px[(size_t)t * DI_]);
            const float dtx = dt_v * xv;
            S += dt_v;
#pragma unroll
            for (int n = 0; n < N_; ++n) {
                const float dA = exp2f(dt_v * A2[n]);
                hs[n] = fmaf(hs[n], dA, dtx * bsh[wave][t][n]);
            }
        }
    }

    sS[(size_t)chunk * (B_ * DI_) + (size_t)(bh * P_ + lane)] = S;
    const size_t s0 = (size_t)chunk * NSEQ_ + ((size_t)(bh * P_ + lane)) * N_;
    f16x8 h0, h1;
#pragma unroll
    for (int j = 0; j < 8; ++j) { h0[j] = (_Float16)hs[j]; h1[j] = (_Float16)hs[8 + j]; }
    *reinterpret_cast<f16x8*>(st_hend + s0) = h0;
    *reinterpret_cast<f16x8*>(st_hend + s0 + 8) = h1;
}

// combine reads scalar S + A_log; st arrays fp16; 256 blocks x 128 threads.
__launch_bounds__(128)
__global__ void scan_combine(const float* __restrict__ sS,
                             const float* __restrict__ A_log,
                             _Float16* __restrict__ st_prod,
                             const _Float16* __restrict__ st_hend) {
    const int s = blockIdx.x * 128 + threadIdx.x;
    const int seqc = s >> 4;               // b*512 + h*64 + p
    const int n = s & 15;
    const int cA = seqc & (DI_ - 1);       // h*64 + p
    const float A2n = -__expf(A_log[cA * N_ + n]) * LOG2E_;
    float H = 0.f;
#pragma unroll 8
    for (int k = 0; k < NC_; ++k) {
        const size_t o = (size_t)k * NSEQ_ + s;
        const float Pv = exp2f(A2n * sS[(size_t)k * (B_ * DI_) + seqc]);
        const float Ev = (float)st_hend[o];
        st_prod[o] = (_Float16)H;
        H = fmaf(Pv, H, Ev);
    }
}

__launch_bounds__(256)
__global__ void scan_chunk_out(const __hip_bfloat16* __restrict__ xi,
                               const __hip_bfloat16* __restrict__ z,
                               const __hip_bfloat16* __restrict__ projb,
                               const float* __restrict__ A_log,
                               const float* __restrict__ D_skip,
                               const _Float16* __restrict__ st_hin,
                               __hip_bfloat16* __restrict__ yg) {
    __shared__ float bc[4][CL_][32];   // 32 KB: per-wave B|C cache
    const int bh = blockIdx.x;
    const int b = bh >> 3;
    const int h = bh & 7;
    const int lane = threadIdx.x & 63;
    const int wave = threadIdx.x >> 6;
    const int chunk = blockIdx.y * 4 + wave;
    const int t0 = chunk * CL_;
    const int c = h * P_ + lane;
    const int bOff = DI_ + h * N_;
    const int cOff = DI_ + H_ * N_ + h * N_;

    // register-stage B and C (bf16 -> fp32 LDS), linear lane->dest
    {
#pragma unroll
        for (int r = 0; r < 8; ++r) {
            const int stp = r * 8 + (lane >> 3);
            const int j = (lane & 7) * 4;            // 0..28
            const int soff = (j < 16) ? (bOff + j) : (cOff + (j - 16));
            const bf16x4 v = *reinterpret_cast<const bf16x4*>(
                projb + ((size_t)b * L_ + t0 + stp) * PROJ_ + soff);
            *reinterpret_cast<float4*>(&bc[wave][stp][j]) =
                make_float4((float)v[0], (float)v[1], (float)v[2], (float)v[3]);
        }
    }

    float A2[N_];
#pragma unroll
    for (int n = 0; n < N_; ++n)
        A2[n] = -__expf(A_log[c * N_ + n]) * LOG2E_;
    const bool fast = a_is_arith(A2);
    const float Dv = D_skip[c];

    const size_t s0 = (size_t)chunk * NSEQ_ + ((size_t)(bh * P_ + lane)) * N_;
    const __hip_bfloat16* pDt = projb + ((size_t)b * L_ + t0) * PROJ_ + c;
    const __hip_bfloat16* px = xi + ((size_t)b * L_ + t0) * DI_ + c;
    const __hip_bfloat16* pz = z + ((size_t)b * L_ + t0) * DI_ + c;
    __hip_bfloat16* py = yg + ((size_t)b * L_ + t0) * DI_ + c;

    if (fast) {
        // R6: packed fp32 — state pairs + y even/odd partial sums
        f32x2 hp[8];
        {
            const f16x8 a0 = *reinterpret_cast<const f16x8*>(st_hin + s0);
            const f16x8 a1 = *reinterpret_cast<const f16x8*>(st_hin + s0 + 8);
#pragma unroll
            for (int p = 0; p < 4; ++p) {
                hp[p][0] = (float)a0[2 * p]; hp[p][1] = (float)a0[2 * p + 1];
                hp[4 + p][0] = (float)a1[2 * p]; hp[4 + p][1] = (float)a1[2 * p + 1];
            }
        }
        float dtb[2][4], xb[2][4], zb[2][4];
#pragma unroll
        for (int i = 0; i < 4; ++i) {
            dtb[0][i] = __bfloat162float(pDt[(size_t)i * PROJ_]);
            xb[0][i] = __bfloat162float(px[(size_t)i * DI_]);
            zb[0][i] = __bfloat162float(pz[(size_t)i * DI_]);
        }
#pragma unroll
        for (int k = 0; k < CL_ / 4; ++k) {
            const int cur = k & 1, nxt = cur ^ 1;
            if (k + 1 < CL_ / 4) {
#pragma unroll
                for (int i = 0; i < 4; ++i) {
                    const int t = (k + 1) * 4 + i;
                    dtb[nxt][i] = __bfloat162float(pDt[(size_t)t * PROJ_]);
                    xb[nxt][i] = __bfloat162float(px[(size_t)t * DI_]);
                    zb[nxt][i] = __bfloat162float(pz[(size_t)t * DI_]);
                }
            }
#pragma unroll
            for (int i = 0; i < 4; ++i) {
                const int t = k * 4 + i;
                const float dt_v = dtb[cur][i];
                const float xv = xb[cur][i];
                const float zv = zb[cur][i];
                const float dtx = dt_v * xv;
                const float e1 = exp2f(dt_v * A2[0]);
                const float e2 = e1 * e1;
                f32x2 dp; dp[0] = e1; dp[1] = e2;
                f32x2 mm; mm[0] = e2; mm[1] = e2;
                f32x2 dd; dd[0] = dtx; dd[1] = dtx;
                f32x2 yp = (f32x2)0.f;
                const f32x4* bp = reinterpret_cast<const f32x4*>(&bc[wave][t][0]);
#pragma unroll
                for (int q = 0; q < 4; ++q) {
                    const f32x4 Bq = bp[q];
                    const f32x4 Cq = bp[4 + q];
                    f32x2 b0; b0[0] = Bq[0]; b0[1] = Bq[1];
                    f32x2 b1; b1[0] = Bq[2]; b1[1] = Bq[3];
                    f32x2 c0; c0[0] = Cq[0]; c0[1] = Cq[1];
                    f32x2 c1; c1[0] = Cq[2]; c1[1] = Cq[3];
                    hp[2 * q] = pk_fma(hp[2 * q], dp, pk_mul(dd, b0));
                    yp = pk_fma(hp[2 * q], c0, yp);
                    dp = pk_mul(dp, mm);
                    hp[2 * q + 1] = pk_fma(hp[2 * q + 1], dp, pk_mul(dd, b1));
                    yp = pk_fma(hp[2 * q + 1], c1, yp);
                    dp = pk_mul(dp, mm);
                }
                const float y = yp[0] + yp[1];
                const float g = zv / (1.f + __expf(-zv));
                py[(size_t)t * DI_] = __float2bfloat16((y + Dv * xv) * g);
            }
        }
    } else {
        float hs[N_];
        {
            const f16x8 a0 = *reinterpret_cast<const f16x8*>(st_hin + s0);
            const f16x8 a1 = *reinterpret_cast<const f16x8*>(st_hin + s0 + 8);
#pragma unroll
            for (int j = 0; j < 8; ++j) { hs[j] = (float)a0[j]; hs[8 + j] = (float)a1[j]; }
        }
#pragma unroll 4
        for (int t = 0; t < CL_; ++t) {
            const float dt_v = __bfloat162float(pDt[(size_t)t * PROJ_]);
            const float xv = __bfloat162float(px[(size_t)t * DI_]);
            const float zv = __bfloat162float(pz[(size_t)t * DI_]);
            const float dtx = dt_v * xv;
            float y = 0.f;
#pragma unroll
            for (int n = 0; n < N_; ++n) {
                const float dA = exp2f(dt_v * A2[n]);
                hs[n] = fmaf(hs[n], dA, dtx * bc[wave][t][n]);
                y = fmaf(hs[n], bc[wave][t][16 + n], y);
            }
            const float g = zv / (1.f + __expf(-zv));
            py[(size_t)t * DI_] = __float2bfloat16((y + Dv * xv) * g);
        }
    }
}

// ---------------- host launcher --------------------------------------------
extern "C" void kernel_launch(void* const* d_in, const int* in_sizes, int n_in,
                              void* d_out, int out_size, void* d_ws, size_t ws_size,
                              hipStream_t stream) {
    const float* inputs = (const float*)d_in[0];
    const float* f_in_w = (const float*)d_in[1];
    const float* f_in_b = (const float*)d_in[2];
    const float* f_xp_w = (const float*)d_in[3];
    const float* f_xp_b = (const float*)d_in[4];
    const float* f_dt_b = (const float*)d_in[5];
    const float* f_A = (const float*)d_in[6];
    const float* f_D = (const float*)d_in[7];
    const float* f_out_w = (const float*)d_in[8];
    const float* f_out_b = (const float*)d_in[9];
    const float* b_in_w = (const float*)d_in[10];
    const float* b_in_b = (const float*)d_in[11];
    const float* b_xp_w = (const float*)d_in[12];
    const float* b_xp_b = (const float*)d_in[13];
    const float* b_dt_b = (const float*)d_in[14];
    const float* b_A = (const float*)d_in[15];
    const float* b_D = (const float*)d_in[16];
    const float* b_out_w = (const float*)d_in[17];
    const float* b_out_b = (const float*)d_in[18];
    const float* norm_w = (const float*)d_in[19];
    const float* norm_b = (const float*)d_in[20];
    const float* conv_w = (const float*)d_in[21];
    const float* conv_b = (const float*)d_in[22];
    float* out = (float*)d_out;

    // workspace layout (slot sizes kept from the NC=128 layout; usage shrank)
    float* ws = (float*)d_ws;
    _Float16* st_prod = (_Float16*)ws;                    // <= NSEQ_*64 f16
    float* slot1 = ws + (size_t)NSEQ_ * 128;
    _Float16* st_hend = (_Float16*)slot1;                 // <= NSEQ_*64 f16
    float* zslot   = slot1 + (size_t)NSEQ_ * 128;
    __hip_bfloat16* z_bf = (__hip_bfloat16*)zslot;
    float* pslot   = zslot + (size_t)M_ * DI_;            // proj slot
    __hip_bfloat16* proj_bf = (__hip_bfloat16*)pslot;     // M*768 bf16 = 25 MB
    float* y1      = pslot + (size_t)M_ * PROJ_;          // slot: sS
    float* sS      = y1;                                  // NC_*2048 f32 used
    __hip_bfloat16* xi_bf = (__hip_bfloat16*)(y1 + (size_t)M_ * D_);
    __hip_bfloat16* yg_bf = xi_bf + (size_t)M_ * DI_;
    __hip_bfloat16* a_bf  = yg_bf + (size_t)M_ * DI_;
    __hip_bfloat16* wpool = a_bf + (size_t)M_ * D_;
    __hip_bfloat16* f_in_wb  = wpool;
    __hip_bfloat16* f_xp_wb  = f_in_wb + 2 * DI_ * D_;
    __hip_bfloat16* f_out_wb = f_xp_wb + PROJ_ * DI_;
    __hip_bfloat16* b_in_wb  = f_out_wb + D_ * DI_;
    __hip_bfloat16* b_xp_wb  = b_in_wb + 2 * DI_ * D_;
    __hip_bfloat16* b_out_wb = b_xp_wb + PROJ_ * DI_;

    const dim3 blk(256);
    const dim3 g_in(M_ / 128, (2 * DI_) / 128);   // (128,8)
    const dim3 g_xp(M_ / 128, PROJ_ / 128);       // (128,6)
    const dim3 g_out64(M_ / 64, D_ / 64);         // (256,4) bwd out_proj
    const dim3 g_oln(M_ / 64);                    // 256 blocks fwd out_proj+LN
    const dim3 g_chunk(B_ * H_, NC_ / 4);         // (32,16)
    const dim3 g_comb(NSEQ_ / 128);               // 256 blocks x 128 thr
    const dim3 blk_comb(128);

    // ---- fp32 -> bf16 weight conversions (inputs handled in-GEMM) ----
    f2b_all<<<dim3(1024), blk, 0, stream>>>(f_in_w, f_xp_w, f_out_w,
                                            b_in_w, b_xp_w, b_out_w,
                                            f_in_wb, f_xp_wb, f_out_wb,
                                            b_in_wb, b_xp_wb, b_out_wb);

    // ---- forward pass ----
    gemm_mfma<1, 1><<<g_in, blk, 0, stream>>>(nullptr, f_in_wb, f_in_b, D_,
                                              z_bf, xi_bf, nullptr, inputs);
    gemm_mfma<2, 0><<<g_xp, blk, 0, stream>>>(xi_bf, f_xp_wb, f_xp_b, DI_,
                                              nullptr, proj_bf, f_dt_b, nullptr);
    scan_chunk_state<<<g_chunk, blk, 0, stream>>>(xi_bf, proj_bf, f_A,
                                                  sS, st_hend);
    scan_combine<<<g_comb, blk_comb, 0, stream>>>(sS, f_A, st_prod, st_hend);
    scan_chunk_out<<<g_chunk, blk, 0, stream>>>(xi_bf, z_bf, proj_bf, f_A, f_D,
                                                st_prod, yg_bf);
    gemm_out_ln<<<g_oln, blk, 0, stream>>>(yg_bf, f_out_wb, f_out_b,
                                           norm_w, norm_b, a_bf);

    // ---- backward pass ----
    gemm_mfma<1, 0><<<g_in, blk, 0, stream>>>(a_bf, b_in_wb, b_in_b, D_,
                                              z_bf, xi_bf, nullptr, nullptr);
    gemm_mfma<2, 0><<<g_xp, blk, 0, stream>>>(xi_bf, b_xp_wb, b_xp_b, DI_,
                                              nullptr, proj_bf, b_dt_b, nullptr);
    scan_chunk_state<<<g_chunk, blk, 0, stream>>>(xi_bf, proj_bf, b_A,
                                                  sS, st_hend);
    scan_combine<<<g_comb, blk_comb, 0, stream>>>(sS, b_A, st_prod, st_hend);
    scan_chunk_out<<<g_chunk, blk, 0, stream>>>(xi_bf, z_bf, proj_bf, b_A, b_D,
                                                st_prod, yg_bf);
    gemm64_convout<<<g_out64, blk, 0, stream>>>(yg_bf, b_out_wb, b_out_b, DI_,
                                                out, conv_w, conv_b, inputs);
}

// Round 7
// 356.281 us; speedup vs baseline: 1.0397x; 1.0397x over previous
//
#include <hip/hip_runtime.h>
#include <hip/hip_bf16.h>
#include <cstdint>
#include <cstddef>

// ---------------- problem constants ----------------
#define B_  4
#define L_  4096
#define D_  256
#define DI_ 512
#define H_  8
#define P_  64
#define N_  16
#define M_  (B_ * L_)              // 16384 rows
#define PROJ_ (DI_ + 2 * H_ * N_)  // 768

// chunked scan parameters (1 thread = 1 (b,h,p) channel, 16 states)
#define NC_ 64                     // chunks along L
#define CL_ (L_ / NC_)             // 64
#define NSEQ_ (B_ * H_ * P_ * N_)  // 32768 scalar sequences
#define LOG2E_ 1.4426950408889634f

typedef __bf16 bf16x8 __attribute__((ext_vector_type(8)));
typedef __bf16 bf16x4 __attribute__((ext_vector_type(4)));
typedef float f32x4 __attribute__((ext_vector_type(4)));
typedef _Float16 f16x8 __attribute__((ext_vector_type(8)));

__device__ __forceinline__ void cp16_lds(const __hip_bfloat16* g, short* lds) {
    __builtin_amdgcn_global_load_lds(
        (const __attribute__((address_space(1))) void*)g,
        (__attribute__((address_space(3))) void*)lds, 16, 0, 0);
}

// ---------------- fp32 -> bf16 conversion, weights only ----------------------
// R7: float4-vectorized (8 elems/thread). All segment sizes are multiples of 8.
#define WS1 (2 * DI_ * D_)     // in_proj_w    262144
#define WS2 (PROJ_ * DI_)      // x_proj_w     393216
#define WS3 (D_ * DI_)         // out_proj_w   131072
#define WC1 (WS1)
#define WC2 (WC1 + WS2)
#define WC3 (WC2 + WS3)
#define WC4 (WC3 + WS1)
#define WC5 (WC4 + WS2)
#define WC6 (WC5 + WS3)        // 1572864 total
#define WT8 (WC6 / 8)          // 196608 vec8 work items

__launch_bounds__(256)
__global__ void f2b_all(const float* __restrict__ i1,
                        const float* __restrict__ i2, const float* __restrict__ i3,
                        const float* __restrict__ i4, const float* __restrict__ i5,
                        const float* __restrict__ i6,
                        __hip_bfloat16* o1, __hip_bfloat16* o2,
                        __hip_bfloat16* o3, __hip_bfloat16* o4, __hip_bfloat16* o5,
                        __hip_bfloat16* o6) {
    for (int idx8 = blockIdx.x * 256 + threadIdx.x; idx8 < WT8;
         idx8 += gridDim.x * 256) {
        const int idx = idx8 * 8;
        const float* s; __hip_bfloat16* d; int off;
        if (idx < WC1)      { s = i1; d = o1; off = idx; }
        else if (idx < WC2) { s = i2; d = o2; off = idx - WC1; }
        else if (idx < WC3) { s = i3; d = o3; off = idx - WC2; }
        else if (idx < WC4) { s = i4; d = o4; off = idx - WC3; }
        else if (idx < WC5) { s = i5; d = o5; off = idx - WC4; }
        else                { s = i6; d = o6; off = idx - WC5; }
        const float4 f0 = *reinterpret_cast<const float4*>(s + off);
        const float4 f1 = *reinterpret_cast<const float4*>(s + off + 4);
        bf16x8 v;
        v[0] = (__bf16)f0.x; v[1] = (__bf16)f0.y;
        v[2] = (__bf16)f0.z; v[3] = (__bf16)f0.w;
        v[4] = (__bf16)f1.x; v[5] = (__bf16)f1.y;
        v[6] = (__bf16)f1.z; v[7] = (__bf16)f1.w;
        *reinterpret_cast<bf16x8*>(d + off) = v;
    }
}

// ---------------- MFMA bf16 GEMM 128x128: C = A * W^T + bias -----------------
// BK=64, XOR-swizzled LDS -> conflict-free ds_read_b128.
// AF32=1: A read as fp32; pre-swizzled global src + linear ds_write.
// EPI 1: in_proj: col<DI -> silu -> obf bf16 (xi, ld 512); else z bf16 (zb)
// EPI 2: x_proj: col<DI -> softplus(v+aux); bf16 store to obf (ld 768)
template <int EPI, int AF32>
__launch_bounds__(256)
__global__ void gemm_mfma(const __hip_bfloat16* __restrict__ A,
                          const __hip_bfloat16* __restrict__ W,
                          const float* __restrict__ bias, int Kv,
                          __hip_bfloat16* __restrict__ zb,
                          __hip_bfloat16* __restrict__ obf,
                          const float* __restrict__ aux,
                          const float* __restrict__ A32) {
    __shared__ short As[128 * 64];   // 16 KB
    __shared__ short Bs[128 * 64];   // 16 KB
    const int tid = threadIdx.x;
    const int lane = tid & 63;
    const int wave = tid >> 6;
    const int bm = blockIdx.x * 128;
    const int bn = blockIdx.y * 128;
    const int wm = (wave >> 1) * 64;
    const int wn = (wave & 1) * 64;

    f32x4 acc[4][4];
#pragma unroll
    for (int i = 0; i < 4; ++i)
#pragma unroll
        for (int j = 0; j < 4; ++j) acc[i][j] = (f32x4)0.f;

    const int srow = lane >> 3;                       // 0..7
    const int sx = lane & 7;
    const int ssegx = (sx ^ srow) * 8;                // swizzled k offset (shorts)
    const __hip_bfloat16* gA0 = A + (size_t)(bm + wave * 32 + srow) * Kv + ssegx;
    const __hip_bfloat16* gB0 = W + (size_t)(bn + wave * 32 + srow) * Kv + ssegx;
    short* lA0 = As + (wave * 32) * 64;
    short* lB0 = Bs + (wave * 32) * 64;

    const int fr = lane & 15;        // fragment row within 16
    const int kq = lane >> 4;        // k-quarter 0..3

    for (int k0 = 0; k0 < Kv; k0 += 64) {
        if (AF32) {
#pragma unroll
            for (int rb = 0; rb < 4; ++rb) {
                const int row = wave * 32 + rb * 8 + srow;
                // pre-swizzled global source; linear LDS dest (conflict-free)
                const float* g = A32 + (size_t)(bm + row) * Kv + k0 + ssegx;
                const float4 f0 = *reinterpret_cast<const float4*>(g);
                const float4 f1 = *reinterpret_cast<const float4*>(g + 4);
                bf16x8 s;
                s[0] = (__bf16)f0.x; s[1] = (__bf16)f0.y;
                s[2] = (__bf16)f0.z; s[3] = (__bf16)f0.w;
                s[4] = (__bf16)f1.x; s[5] = (__bf16)f1.y;
                s[6] = (__bf16)f1.z; s[7] = (__bf16)f1.w;
                *reinterpret_cast<bf16x8*>(&As[row * 64 + sx * 8]) = s;
            }
        } else {
#pragma unroll
            for (int rb = 0; rb < 4; ++rb)
                cp16_lds(gA0 + (size_t)(rb * 8) * Kv + k0, lA0 + rb * 8 * 64);
        }
#pragma unroll
        for (int rb = 0; rb < 4; ++rb)
            cp16_lds(gB0 + (size_t)(rb * 8) * Kv + k0, lB0 + rb * 8 * 64);
        __syncthreads();
#pragma unroll
        for (int ks = 0; ks < 2; ++ks) {
            const int kgg = ks * 4 + kq;                       // 0..7
            const int kslot = (kgg ^ (fr & 7)) * 8;            // un-swizzle
            bf16x8 af[4], bv[4];
#pragma unroll
            for (int i = 0; i < 4; ++i)
                af[i] = *reinterpret_cast<const bf16x8*>(
                    &As[(wm + i * 16 + fr) * 64 + kslot]);
#pragma unroll
            for (int j = 0; j < 4; ++j)
                bv[j] = *reinterpret_cast<const bf16x8*>(
                    &Bs[(wn + j * 16 + fr) * 64 + kslot]);
#pragma unroll
            for (int i = 0; i < 4; ++i)
#pragma unroll
                for (int j = 0; j < 4; ++j)
                    acc[i][j] = __builtin_amdgcn_mfma_f32_16x16x32_bf16(
                        af[i], bv[j], acc[i][j], 0, 0, 0);
        }
        __syncthreads();
    }

    const int n16 = lane & 15;
    const int r4 = (lane >> 4) * 4;
#pragma unroll
    for (int i = 0; i < 4; ++i) {
#pragma unroll
        for (int j = 0; j < 4; ++j) {
            const int cg = bn + wn + j * 16 + n16;
            const float bb = bias[cg];
#pragma unroll
            for (int v = 0; v < 4; ++v) {
                const int r = bm + wm + i * 16 + r4 + v;
                float val = acc[i][j][v] + bb;
                if (EPI == 1) {
                    if (cg < DI_) {
                        val = val / (1.f + __expf(-val));
                        obf[(size_t)r * DI_ + cg] = __float2bfloat16(val);
                    } else {
                        zb[(size_t)r * DI_ + cg - DI_] = __float2bfloat16(val);
                    }
                } else {  // EPI 2: all-bf16 proj store
                    if (cg < DI_) {
                        const float x = val + aux[cg];
                        val = (x > 20.f) ? x : __logf(1.f + __expf(x));
                    }
                    obf[(size_t)r * PROJ_ + cg] = __float2bfloat16(val);
                }
            }
        }
    }
}

// ---------------- small-tile GEMM 64x64: bwd out_proj + conv/GELU ------------
__launch_bounds__(256)
__global__ void gemm64_convout(const __hip_bfloat16* __restrict__ A,
                               const __hip_bfloat16* __restrict__ W,
                               const float* __restrict__ bias, int Kv,
                               float* __restrict__ out0,
                               const float* __restrict__ cw,
                               const float* __restrict__ cb,
                               const float* __restrict__ cinp) {
    __shared__ short As[64 * 64];    // 8 KB
    __shared__ short Bs[64 * 64];    // 8 KB
    const int tid = threadIdx.x;
    const int lane = tid & 63;
    const int wave = tid >> 6;
    const int bm = blockIdx.x * 64;
    const int bn = blockIdx.y * 64;
    const int wm = (wave >> 1) * 32;
    const int wn = (wave & 1) * 32;

    f32x4 acc[2][2];
#pragma unroll
    for (int i = 0; i < 2; ++i)
#pragma unroll
        for (int j = 0; j < 2; ++j) acc[i][j] = (f32x4)0.f;

    const int srow = lane >> 3;
    const int ssegx = ((lane & 7) ^ srow) * 8;
    const __hip_bfloat16* gA0 = A + (size_t)(bm + wave * 16 + srow) * Kv + ssegx;
    const __hip_bfloat16* gB0 = W + (size_t)(bn + wave * 16 + srow) * Kv + ssegx;
    short* lA0 = As + (wave * 16) * 64;
    short* lB0 = Bs + (wave * 16) * 64;

    const int fr = lane & 15;
    const int kq = lane >> 4;

    for (int k0 = 0; k0 < Kv; k0 += 64) {
#pragma unroll
        for (int rb = 0; rb < 2; ++rb) {
            cp16_lds(gA0 + (size_t)(rb * 8) * Kv + k0, lA0 + rb * 8 * 64);
            cp16_lds(gB0 + (size_t)(rb * 8) * Kv + k0, lB0 + rb * 8 * 64);
        }
        __syncthreads();
#pragma unroll
        for (int ks = 0; ks < 2; ++ks) {
            const int kgg = ks * 4 + kq;
            const int kslot = (kgg ^ (fr & 7)) * 8;
            bf16x8 af[2], bv[2];
#pragma unroll
            for (int i = 0; i < 2; ++i)
                af[i] = *reinterpret_cast<const bf16x8*>(
                    &As[(wm + i * 16 + fr) * 64 + kslot]);
#pragma unroll
            for (int j = 0; j < 2; ++j)
                bv[j] = *reinterpret_cast<const bf16x8*>(
                    &Bs[(wn + j * 16 + fr) * 64 + kslot]);
#pragma unroll
            for (int i = 0; i < 2; ++i)
#pragma unroll
                for (int j = 0; j < 2; ++j)
                    acc[i][j] = __builtin_amdgcn_mfma_f32_16x16x32_bf16(
                        af[i], bv[j], acc[i][j], 0, 0, 0);
        }
        __syncthreads();
    }

    const int n16 = lane & 15;
    const int r4 = (lane >> 4) * 4;
#pragma unroll
    for (int i = 0; i < 2; ++i) {
#pragma unroll
        for (int j = 0; j < 2; ++j) {
            const int cg = bn + wn + j * 16 + n16;
            const float bb = bias[cg];
#pragma unroll
            for (int v = 0; v < 4; ++v) {
                const int r = bm + wm + i * 16 + r4 + v;
                float val = acc[i][j][v] + bb;
                const int b = r >> 12;
                const int l = r & (L_ - 1);
                const int lo = L_ - 1 - l;
                const size_t base = ((size_t)(b << 12) + lo) * 256 + cg;
                float cv = fmaf(cinp[base], cw[cg * 3 + 1], cb[cg]);
                if (lo > 0) cv = fmaf(cinp[base - 256], cw[cg * 3 + 0], cv);
                if (lo + 1 < L_) cv = fmaf(cinp[base + 256], cw[cg * 3 + 2], cv);
                const float g = 0.5f * cv * (1.f + erff(cv * 0.70710678118654752f));
                out0[base] = val + g;
            }
        }
    }
}

// ---------------- fwd out_proj + LayerNorm + flip, 64-row tiles --------------
__launch_bounds__(256)
__global__ void gemm_out_ln(const __hip_bfloat16* __restrict__ A,
                            const __hip_bfloat16* __restrict__ W,
                            const float* __restrict__ bias,
                            const float* __restrict__ lnw,
                            const float* __restrict__ lnb,
                            __hip_bfloat16* __restrict__ outb) {
    __shared__ short As[64 * 64];     // 8 KB
    __shared__ short Ws[256 * 64];    // 32 KB
    __shared__ float rs[2][4][64];    // 2 KB row partial sums
    const int tid = threadIdx.x;
    const int lane = tid & 63;
    const int wave = tid >> 6;
    const int bm = blockIdx.x * 64;
    const int Kv = DI_;

    f32x4 acc[4][4];
#pragma unroll
    for (int i = 0; i < 4; ++i)
#pragma unroll
        for (int j = 0; j < 4; ++j) acc[i][j] = (f32x4)0.f;

    const int srow = lane >> 3;
    const int ssegx = ((lane & 7) ^ srow) * 8;
    const __hip_bfloat16* gA0 = A + (size_t)(bm + wave * 16 + srow) * Kv + ssegx;
    const __hip_bfloat16* gW0 = W + (size_t)(wave * 64 + srow) * Kv + ssegx;
    short* lA0 = As + (wave * 16) * 64;
    short* lW0 = Ws + (wave * 64) * 64;

    const int fr = lane & 15;
    const int kq = lane >> 4;

    for (int k0 = 0; k0 < Kv; k0 += 64) {
#pragma unroll
        for (int rb = 0; rb < 2; ++rb)
            cp16_lds(gA0 + (size_t)(rb * 8) * Kv + k0, lA0 + rb * 8 * 64);
#pragma unroll
        for (int rb = 0; rb < 8; ++rb)
            cp16_lds(gW0 + (size_t)(rb * 8) * Kv + k0, lW0 + rb * 8 * 64);
        __syncthreads();
#pragma unroll
        for (int ks = 0; ks < 2; ++ks) {
            const int kgg = ks * 4 + kq;
            const int kslot = (kgg ^ (fr & 7)) * 8;
            bf16x8 af[4], bv[4];
#pragma unroll
            for (int i = 0; i < 4; ++i)
                af[i] = *reinterpret_cast<const bf16x8*>(
                    &As[(i * 16 + fr) * 64 + kslot]);
#pragma unroll
            for (int j = 0; j < 4; ++j)
                bv[j] = *reinterpret_cast<const bf16x8*>(
                    &Ws[(wave * 64 + j * 16 + fr) * 64 + kslot]);
#pragma unroll
            for (int i = 0; i < 4; ++i)
#pragma unroll
                for (int j = 0; j < 4; ++j)
                    acc[i][j] = __builtin_amdgcn_mfma_f32_16x16x32_bf16(
                        af[i], bv[j], acc[i][j], 0, 0, 0);
        }
        __syncthreads();
    }

    const int n16 = lane & 15;
    const int r4 = (lane >> 4) * 4;
#pragma unroll
    for (int j = 0; j < 4; ++j) {
        const float bb = bias[wave * 64 + j * 16 + n16];
#pragma unroll
        for (int i = 0; i < 4; ++i)
#pragma unroll
            for (int v = 0; v < 4; ++v) acc[i][j][v] += bb;
    }

    // per-wave row partial sums over this wave's 64-col slice
#pragma unroll
    for (int i = 0; i < 4; ++i) {
#pragma unroll
        for (int v = 0; v < 4; ++v) {
            float s = 0.f, s2 = 0.f;
#pragma unroll
            for (int j = 0; j < 4; ++j) {
                const float t = acc[i][j][v];
                s += t; s2 = fmaf(t, t, s2);
            }
            s += __shfl_xor(s, 1); s2 += __shfl_xor(s2, 1);
            s += __shfl_xor(s, 2); s2 += __shfl_xor(s2, 2);
            s += __shfl_xor(s, 4); s2 += __shfl_xor(s2, 4);
            s += __shfl_xor(s, 8); s2 += __shfl_xor(s2, 8);
            if (n16 == 0) {
                rs[0][wave][i * 16 + r4 + v] = s;
                rs[1][wave][i * 16 + r4 + v] = s2;
            }
        }
    }
    __syncthreads();

#pragma unroll
    for (int i = 0; i < 4; ++i) {
#pragma unroll
        for (int v = 0; v < 4; ++v) {
            const int row = i * 16 + r4 + v;
            const float ts = rs[0][0][row] + rs[0][1][row] + rs[0][2][row] + rs[0][3][row];
            const float ts2 = rs[1][0][row] + rs[1][1][row] + rs[1][2][row] + rs[1][3][row];
            const float mean = ts * (1.f / 256.f);
            const float var = ts2 * (1.f / 256.f) - mean * mean;
            const float inv = rsqrtf(var + 1e-5f);
            const int rg = bm + row;
            const int b = rg >> 12;
            const int l = rg & (L_ - 1);
            const size_t drow = (size_t)((b << 12) + (L_ - 1 - l)) * 256;
#pragma unroll
            for (int j = 0; j < 4; ++j) {
                const int cg = wave * 64 + j * 16 + n16;
                const float o = (acc[i][j][v] - mean) * inv * lnw[cg] + lnb[cg];
                outb[drow + cg] = __float2bfloat16(o);
            }
        }
    }
}

// ---------------- chunked selective scan (R5 scalar form) --------------------
__device__ __forceinline__ bool a_is_arith(const float* A2) {
    bool ok = true;
#pragma unroll
    for (int n = 1; n < N_; ++n)
        ok = ok && (fabsf(A2[n] - (float)(n + 1) * A2[0]) <= 1e-4f * fabsf(A2[n]));
    return ok;
}

__launch_bounds__(256)
__global__ void scan_chunk_state(const __hip_bfloat16* __restrict__ xi,
                                 const __hip_bfloat16* __restrict__ projb,
                                 const float* __restrict__ A_log,
                                 float* __restrict__ sS,
                                 _Float16* __restrict__ st_hend) {
    __shared__ float bsh[4][CL_][16];   // 16 KB: per-wave B cache
    const int bh = blockIdx.x;
    const int b = bh >> 3;
    const int h = bh & 7;
    const int lane = threadIdx.x & 63;
    const int wave = threadIdx.x >> 6;
    const int chunk = blockIdx.y * 4 + wave;
    const int t0 = chunk * CL_;
    const int c = h * P_ + lane;
    const int bOff = DI_ + h * N_;

    // register-stage B (bf16 -> fp32 LDS), linear lane->dest (conflict-free)
    {
#pragma unroll
        for (int r = 0; r < 4; ++r) {
            const int stp = r * 16 + (lane >> 2);
            const int j = (lane & 3) * 4;
            const bf16x4 v = *reinterpret_cast<const bf16x4*>(
                projb + ((size_t)b * L_ + t0 + stp) * PROJ_ + bOff + j);
            *reinterpret_cast<float4*>(&bsh[wave][stp][j]) =
                make_float4((float)v[0], (float)v[1], (float)v[2], (float)v[3]);
        }
    }

    float A2[N_], hs[N_];
#pragma unroll
    for (int n = 0; n < N_; ++n) {
        A2[n] = -__expf(A_log[c * N_ + n]) * LOG2E_;
        hs[n] = 0.f;
    }
    const bool fast = a_is_arith(A2);

    const __hip_bfloat16* pDt = projb + ((size_t)b * L_ + t0) * PROJ_ + c;
    const __hip_bfloat16* px = xi + ((size_t)b * L_ + t0) * DI_ + c;
    float S = 0.f;

    if (fast) {
        float dtb[2][4], xb[2][4];
#pragma unroll
        for (int i = 0; i < 4; ++i) {
            dtb[0][i] = __bfloat162float(pDt[(size_t)i * PROJ_]);
            xb[0][i] = __bfloat162float(px[(size_t)i * DI_]);
        }
#pragma unroll
        for (int k = 0; k < CL_ / 4; ++k) {
            const int cur = k & 1, nxt = cur ^ 1;
            if (k + 1 < CL_ / 4) {
#pragma unroll
                for (int i = 0; i < 4; ++i) {
                    dtb[nxt][i] = __bfloat162float(pDt[(size_t)((k + 1) * 4 + i) * PROJ_]);
                    xb[nxt][i] = __bfloat162float(px[(size_t)((k + 1) * 4 + i) * DI_]);
                }
            }
#pragma unroll
            for (int i = 0; i < 4; ++i) {
                const int t = k * 4 + i;
                const float dt_v = dtb[cur][i];
                const float dtx = dt_v * xb[cur][i];
                const float e1 = exp2f(dt_v * A2[0]);
                S += dt_v;
                const f32x4* bp = reinterpret_cast<const f32x4*>(&bsh[wave][t][0]);
                float dA = e1;
#pragma unroll
                for (int q = 0; q < 4; ++q) {
                    const f32x4 Bq = bp[q];
#pragma unroll
                    for (int j = 0; j < 4; ++j) {
                        hs[q * 4 + j] = fmaf(hs[q * 4 + j], dA, dtx * Bq[j]);
                        dA *= e1;
                    }
                }
            }
        }
    } else {
#pragma unroll 4
        for (int t = 0; t < CL_; ++t) {
            const float dt_v = __bfloat162float(pDt[(size_t)t * PROJ_]);
            const float xv = __bfloat162float(px[(size_t)t * DI_]);
            const float dtx = dt_v * xv;
            S += dt_v;
#pragma unroll
            for (int n = 0; n < N_; ++n) {
                const float dA = exp2f(dt_v * A2[n]);
                hs[n] = fmaf(hs[n], dA, dtx * bsh[wave][t][n]);
            }
        }
    }

    sS[(size_t)chunk * (B_ * DI_) + (size_t)(bh * P_ + lane)] = S;
    const size_t s0 = (size_t)chunk * NSEQ_ + ((size_t)(bh * P_ + lane)) * N_;
    f16x8 h0, h1;
#pragma unroll
    for (int j = 0; j < 8; ++j) { h0[j] = (_Float16)hs[j]; h1[j] = (_Float16)hs[8 + j]; }
    *reinterpret_cast<f16x8*>(st_hend + s0) = h0;
    *reinterpret_cast<f16x8*>(st_hend + s0 + 8) = h1;
}

// R7: lane-pair split scan — thread u in {0,1} scans 32 chunks locally while
// tracking cumulative decay D; u=1 fixes up H_k = H'_k + D_k * H_mid after one
// shfl (induction: H_{k+1} = Pv H_k + Ev preserved). Critical path 64 -> ~32.
__launch_bounds__(128)
__global__ void scan_combine(const float* __restrict__ sS,
                             const float* __restrict__ A_log,
                             _Float16* __restrict__ st_prod,
                             const _Float16* __restrict__ st_hend) {
    const int gtid = blockIdx.x * 128 + threadIdx.x;
    const int s = gtid >> 1;               // sequence id
    const int u = gtid & 1;                // chunk half
    const int lane = threadIdx.x & 63;
    const int seqc = s >> 4;               // b*512 + h*64 + p
    const int n = s & 15;
    const int cA = seqc & (DI_ - 1);       // h*64 + p
    const float A2n = -__expf(A_log[cA * N_ + n]) * LOG2E_;

    float Hloc[32], Dr[32];
    float H = 0.f, D = 1.f;
#pragma unroll
    for (int kk = 0; kk < 32; ++kk) {
        const int k = u * 32 + kk;
        const size_t o = (size_t)k * NSEQ_ + s;
        const float Pv = exp2f(A2n * sS[(size_t)k * (B_ * DI_) + seqc]);
        const float Ev = (float)st_hend[o];
        Hloc[kk] = H; Dr[kk] = D;
        H = fmaf(Pv, H, Ev);
        D *= Pv;
    }
    // partner exchange: even lane (u=0) broadcasts its half-end H to the pair
    const float Hmid = __shfl(H, lane & ~1);
    if (u == 0) {
#pragma unroll
        for (int kk = 0; kk < 32; ++kk) {
            const size_t o = (size_t)kk * NSEQ_ + s;
            st_prod[o] = (_Float16)Hloc[kk];
        }
    } else {
#pragma unroll
        for (int kk = 0; kk < 32; ++kk) {
            const size_t o = (size_t)(32 + kk) * NSEQ_ + s;
            st_prod[o] = (_Float16)fmaf(Dr[kk], Hmid, Hloc[kk]);
        }
    }
}

__launch_bounds__(256)
__global__ void scan_chunk_out(const __hip_bfloat16* __restrict__ xi,
                               const __hip_bfloat16* __restrict__ z,
                               const __hip_bfloat16* __restrict__ projb,
                               const float* __restrict__ A_log,
                               const float* __restrict__ D_skip,
                               const _Float16* __restrict__ st_hin,
                               __hip_bfloat16* __restrict__ yg) {
    __shared__ float bc[4][CL_][32];   // 32 KB: per-wave B|C cache
    const int bh = blockIdx.x;
    const int b = bh >> 3;
    const int h = bh & 7;
    const int lane = threadIdx.x & 63;
    const int wave = threadIdx.x >> 6;
    const int chunk = blockIdx.y * 4 + wave;
    const int t0 = chunk * CL_;
    const int c = h * P_ + lane;
    const int bOff = DI_ + h * N_;
    const int cOff = DI_ + H_ * N_ + h * N_;

    // register-stage B and C (bf16 -> fp32 LDS), linear lane->dest
    {
#pragma unroll
        for (int r = 0; r < 8; ++r) {
            const int stp = r * 8 + (lane >> 3);
            const int j = (lane & 7) * 4;            // 0..28
            const int soff = (j < 16) ? (bOff + j) : (cOff + (j - 16));
            const bf16x4 v = *reinterpret_cast<const bf16x4*>(
                projb + ((size_t)b * L_ + t0 + stp) * PROJ_ + soff);
            *reinterpret_cast<float4*>(&bc[wave][stp][j]) =
                make_float4((float)v[0], (float)v[1], (float)v[2], (float)v[3]);
        }
    }

    float A2[N_], hs[N_];
    const size_t s0 = (size_t)chunk * NSEQ_ + ((size_t)(bh * P_ + lane)) * N_;
    {
        const f16x8 a0 = *reinterpret_cast<const f16x8*>(st_hin + s0);
        const f16x8 a1 = *reinterpret_cast<const f16x8*>(st_hin + s0 + 8);
#pragma unroll
        for (int j = 0; j < 8; ++j) { hs[j] = (float)a0[j]; hs[8 + j] = (float)a1[j]; }
    }
#pragma unroll
    for (int n = 0; n < N_; ++n)
        A2[n] = -__expf(A_log[c * N_ + n]) * LOG2E_;
    const bool fast = a_is_arith(A2);
    const float Dv = D_skip[c];

    const __hip_bfloat16* pDt = projb + ((size_t)b * L_ + t0) * PROJ_ + c;
    const __hip_bfloat16* px = xi + ((size_t)b * L_ + t0) * DI_ + c;
    const __hip_bfloat16* pz = z + ((size_t)b * L_ + t0) * DI_ + c;
    __hip_bfloat16* py = yg + ((size_t)b * L_ + t0) * DI_ + c;

    if (fast) {
        float dtb[2][4], xb[2][4], zb[2][4];
#pragma unroll
        for (int i = 0; i < 4; ++i) {
            dtb[0][i] = __bfloat162float(pDt[(size_t)i * PROJ_]);
            xb[0][i] = __bfloat162float(px[(size_t)i * DI_]);
            zb[0][i] = __bfloat162float(pz[(size_t)i * DI_]);
        }
#pragma unroll
        for (int k = 0; k < CL_ / 4; ++k) {
            const int cur = k & 1, nxt = cur ^ 1;
            if (k + 1 < CL_ / 4) {
#pragma unroll
                for (int i = 0; i < 4; ++i) {
                    const int t = (k + 1) * 4 + i;
                    dtb[nxt][i] = __bfloat162float(pDt[(size_t)t * PROJ_]);
                    xb[nxt][i] = __bfloat162float(px[(size_t)t * DI_]);
                    zb[nxt][i] = __bfloat162float(pz[(size_t)t * DI_]);
                }
            }
#pragma unroll
            for (int i = 0; i < 4; ++i) {
                const int t = k * 4 + i;
                const float dt_v = dtb[cur][i];
                const float xv = xb[cur][i];
                const float zv = zb[cur][i];
                const float dtx = dt_v * xv;
                const float e1 = exp2f(dt_v * A2[0]);
                const f32x4* bp = reinterpret_cast<const f32x4*>(&bc[wave][t][0]);
                float dA = e1;
                float y = 0.f;
#pragma unroll
                for (int q = 0; q < 4; ++q) {
                    const f32x4 Bq = bp[q];
                    const f32x4 Cq = bp[4 + q];
#pragma unroll
                    for (int j = 0; j < 4; ++j) {
                        hs[q * 4 + j] = fmaf(hs[q * 4 + j], dA, dtx * Bq[j]);
                        y = fmaf(hs[q * 4 + j], Cq[j], y);
                        dA *= e1;
                    }
                }
                const float g = zv / (1.f + __expf(-zv));
                py[(size_t)t * DI_] = __float2bfloat16((y + Dv * xv) * g);
            }
        }
    } else {
#pragma unroll 4
        for (int t = 0; t < CL_; ++t) {
            const float dt_v = __bfloat162float(pDt[(size_t)t * PROJ_]);
            const float xv = __bfloat162float(px[(size_t)t * DI_]);
            const float zv = __bfloat162float(pz[(size_t)t * DI_]);
            const float dtx = dt_v * xv;
            float y = 0.f;
#pragma unroll
            for (int n = 0; n < N_; ++n) {
                const float dA = exp2f(dt_v * A2[n]);
                hs[n] = fmaf(hs[n], dA, dtx * bc[wave][t][n]);
                y = fmaf(hs[n], bc[wave][t][16 + n], y);
            }
            const float g = zv / (1.f + __expf(-zv));
            py[(size_t)t * DI_] = __float2bfloat16((y + Dv * xv) * g);
        }
    }
}

// ---------------- host launcher --------------------------------------------
extern "C" void kernel_launch(void* const* d_in, const int* in_sizes, int n_in,
                              void* d_out, int out_size, void* d_ws, size_t ws_size,
                              hipStream_t stream) {
    const float* inputs = (const float*)d_in[0];
    const float* f_in_w = (const float*)d_in[1];
    const float* f_in_b = (const float*)d_in[2];
    const float* f_xp_w = (const float*)d_in[3];
    const float* f_xp_b = (const float*)d_in[4];
    const float* f_dt_b = (const float*)d_in[5];
    const float* f_A = (const float*)d_in[6];
    const float* f_D = (const float*)d_in[7];
    const float* f_out_w = (const float*)d_in[8];
    const float* f_out_b = (const float*)d_in[9];
    const float* b_in_w = (const float*)d_in[10];
    const float* b_in_b = (const float*)d_in[11];
    const float* b_xp_w = (const float*)d_in[12];
    const float* b_xp_b = (const float*)d_in[13];
    const float* b_dt_b = (const float*)d_in[14];
    const float* b_A = (const float*)d_in[15];
    const float* b_D = (const float*)d_in[16];
    const float* b_out_w = (const float*)d_in[17];
    const float* b_out_b = (const float*)d_in[18];
    const float* norm_w = (const float*)d_in[19];
    const float* norm_b = (const float*)d_in[20];
    const float* conv_w = (const float*)d_in[21];
    const float* conv_b = (const float*)d_in[22];
    float* out = (float*)d_out;

    // workspace layout (slot sizes kept from the NC=128 layout; usage shrank)
    float* ws = (float*)d_ws;
    _Float16* st_prod = (_Float16*)ws;                    // <= NSEQ_*64 f16
    float* slot1 = ws + (size_t)NSEQ_ * 128;
    _Float16* st_hend = (_Float16*)slot1;                 // <= NSEQ_*64 f16
    float* zslot   = slot1 + (size_t)NSEQ_ * 128;
    __hip_bfloat16* z_bf = (__hip_bfloat16*)zslot;
    float* pslot   = zslot + (size_t)M_ * DI_;            // proj slot
    __hip_bfloat16* proj_bf = (__hip_bfloat16*)pslot;     // M*768 bf16 = 25 MB
    float* y1      = pslot + (size_t)M_ * PROJ_;          // slot: sS
    float* sS      = y1;                                  // NC_*2048 f32 used
    __hip_bfloat16* xi_bf = (__hip_bfloat16*)(y1 + (size_t)M_ * D_);
    __hip_bfloat16* yg_bf = xi_bf + (size_t)M_ * DI_;
    __hip_bfloat16* a_bf  = yg_bf + (size_t)M_ * DI_;
    __hip_bfloat16* wpool = a_bf + (size_t)M_ * D_;
    __hip_bfloat16* f_in_wb  = wpool;
    __hip_bfloat16* f_xp_wb  = f_in_wb + 2 * DI_ * D_;
    __hip_bfloat16* f_out_wb = f_xp_wb + PROJ_ * DI_;
    __hip_bfloat16* b_in_wb  = f_out_wb + D_ * DI_;
    __hip_bfloat16* b_xp_wb  = b_in_wb + 2 * DI_ * D_;
    __hip_bfloat16* b_out_wb = b_xp_wb + PROJ_ * DI_;

    const dim3 blk(256);
    const dim3 g_in(M_ / 128, (2 * DI_) / 128);   // (128,8)
    const dim3 g_xp(M_ / 128, PROJ_ / 128);       // (128,6)
    const dim3 g_out64(M_ / 64, D_ / 64);         // (256,4) bwd out_proj
    const dim3 g_oln(M_ / 64);                    // 256 blocks fwd out_proj+LN
    const dim3 g_chunk(B_ * H_, NC_ / 4);         // (32,16)
    const dim3 g_comb(NSEQ_ * 2 / 128);           // 512 blocks x 128 thr (pairs)
    const dim3 blk_comb(128);

    // ---- fp32 -> bf16 weight conversions (inputs handled in-GEMM) ----
    f2b_all<<<dim3(768), blk, 0, stream>>>(f_in_w, f_xp_w, f_out_w,
                                           b_in_w, b_xp_w, b_out_w,
                                           f_in_wb, f_xp_wb, f_out_wb,
                                           b_in_wb, b_xp_wb, b_out_wb);

    // ---- forward pass ----
    gemm_mfma<1, 1><<<g_in, blk, 0, stream>>>(nullptr, f_in_wb, f_in_b, D_,
                                              z_bf, xi_bf, nullptr, inputs);
    gemm_mfma<2, 0><<<g_xp, blk, 0, stream>>>(xi_bf, f_xp_wb, f_xp_b, DI_,
                                              nullptr, proj_bf, f_dt_b, nullptr);
    scan_chunk_state<<<g_chunk, blk, 0, stream>>>(xi_bf, proj_bf, f_A,
                                                  sS, st_hend);
    scan_combine<<<g_comb, blk_comb, 0, stream>>>(sS, f_A, st_prod, st_hend);
    scan_chunk_out<<<g_chunk, blk, 0, stream>>>(xi_bf, z_bf, proj_bf, f_A, f_D,
                                                st_prod, yg_bf);
    gemm_out_ln<<<g_oln, blk, 0, stream>>>(yg_bf, f_out_wb, f_out_b,
                                           norm_w, norm_b, a_bf);

    // ---- backward pass ----
    gemm_mfma<1, 0><<<g_in, blk, 0, stream>>>(a_bf, b_in_wb, b_in_b, D_,
                                              z_bf, xi_bf, nullptr, nullptr);
    gemm_mfma<2, 0><<<g_xp, blk, 0, stream>>>(xi_bf, b_xp_wb, b_xp_b, DI_,
                                              nullptr, proj_bf, b_dt_b, nullptr);
    scan_chunk_state<<<g_chunk, blk, 0, stream>>>(xi_bf, proj_bf, b_A,
                                                  sS, st_hend);
    scan_combine<<<g_comb, blk_comb, 0, stream>>>(sS, b_A, st_prod, st_hend);
    scan_chunk_out<<<g_chunk, blk, 0, stream>>>(xi_bf, z_bf, proj_bf, b_A, b_D,
                                                st_prod, yg_bf);
    gemm64_convout<<<g_out64, blk, 0, stream>>>(yg_bf, b_out_wb, b_out_b, DI_,
                                                out, conv_w, conv_b, inputs);
}